// Round 1
// baseline (2190.849 us; speedup 1.0000x reference)
//
#include <hip/hip_runtime.h>
#include <cstdint>
#include <cstddef>

#define D 128

// ---------------- Threefry-2x32 (JAX/Random123), host+device ----------------
__host__ __device__ inline uint32_t rotl32(uint32_t v, int d) {
  return (v << d) | (v >> (32 - d));
}

__host__ __device__ inline void threefry2x32(uint32_t k0, uint32_t k1,
                                             uint32_t x0, uint32_t x1,
                                             uint32_t* o0, uint32_t* o1) {
  uint32_t k2 = k0 ^ k1 ^ 0x1BD11BDAu;
  x0 += k0; x1 += k1;
#define TF_RND(r) x0 += x1; x1 = rotl32(x1, (r)); x1 ^= x0;
  TF_RND(13) TF_RND(15) TF_RND(26) TF_RND(6)
  x0 += k1; x1 += k2 + 1u;
  TF_RND(17) TF_RND(29) TF_RND(16) TF_RND(24)
  x0 += k2; x1 += k0 + 2u;
  TF_RND(13) TF_RND(15) TF_RND(26) TF_RND(6)
  x0 += k0; x1 += k1 + 3u;
  TF_RND(17) TF_RND(29) TF_RND(16) TF_RND(24)
  x0 += k1; x1 += k2 + 4u;
  TF_RND(13) TF_RND(15) TF_RND(26) TF_RND(6)
  x0 += k2; x1 += k0 + 5u;
#undef TF_RND
  *o0 = x0; *o1 = x1;
}

// XLA ErfInv32 (Giles) — matches lax.erf_inv lowering for f32.
__device__ inline float erfinv_f32(float x) {
  float w = -log1pf(-x * x);
  float p;
  if (w < 5.0f) {
    w = w - 2.5f;
    p = 2.81022636e-08f;
    p = fmaf(p, w, 3.43273939e-07f);
    p = fmaf(p, w, -3.5233877e-06f);
    p = fmaf(p, w, -4.39150654e-06f);
    p = fmaf(p, w, 0.00021858087f);
    p = fmaf(p, w, -0.00125372503f);
    p = fmaf(p, w, -0.00417768164f);
    p = fmaf(p, w, 0.246640727f);
    p = fmaf(p, w, 1.50140941f);
  } else {
    w = sqrtf(w) - 3.0f;
    p = -0.000200214257f;
    p = fmaf(p, w, 0.000100950558f);
    p = fmaf(p, w, 0.00134934322f);
    p = fmaf(p, w, -0.00367342844f);
    p = fmaf(p, w, 0.00573950773f);
    p = fmaf(p, w, -0.0076224613f);
    p = fmaf(p, w, 0.00943887047f);
    p = fmaf(p, w, 1.00167406f);
    p = fmaf(p, w, 2.83297682f);
  }
  return p * x;
}

// jax.random.normal element i (threefry_partitionable bits: o0 ^ o1, counter (0,i))
__device__ inline float jax_normal_elem(uint32_t k0, uint32_t k1, uint32_t idx) {
  uint32_t o0, o1;
  threefry2x32(k0, k1, 0u, idx, &o0, &o1);
  uint32_t bits = o0 ^ o1;
  float f = __uint_as_float((bits >> 9) | 0x3F800000u) - 1.0f;  // [0,1)
  float u = f * 2.0f + (-0.99999994f);                          // maxval-minval == 2.0f exactly
  u = fmaxf(-0.99999994f, u);
  return 1.41421356237309505f * erfinv_f32(u);
}

// ---------------- Kernels ----------------
// One wave (64 lanes) per row; lane handles cols 2l, 2l+1.
__global__ __launch_bounds__(256) void norm_kernel(
    const float* __restrict__ in, float* __restrict__ out, int N,
    uint32_t k0, uint32_t k1, int add_noise) {
  int t = blockIdx.x * blockDim.x + threadIdx.x;
  int row = t >> 6;
  int lane = t & 63;
  if (row >= N) return;
  size_t base = (size_t)row * D + 2 * lane;
  float2 v = *(const float2*)(in + base);
  if (add_noise) {
    uint32_t idx = (uint32_t)base;  // flat index into (N, D), < 2^32
    v.x = v.x + 0.1f * jax_normal_elem(k0, k1, idx);
    v.y = v.y + 0.1f * jax_normal_elem(k0, k1, idx + 1u);
  }
  float ss = v.x * v.x + v.y * v.y;
#pragma unroll
  for (int off = 32; off > 0; off >>= 1) ss += __shfl_xor(ss, off);
  float nrm = sqrtf(ss);
  float denom = fmaxf(nrm, 1e-12f);
  v.x = v.x / denom;
  v.y = v.y / denom;
  *(float2*)(out + base) = v;
}

// One wave per edge: alpha = sigmoid(<h[src], h[dst]>); aggr[dst] += alpha*h[src]
__global__ __launch_bounds__(256) void edge_kernel(
    const float* __restrict__ h, const int* __restrict__ src,
    const int* __restrict__ dst, float* __restrict__ aggr, int E) {
  int t = blockIdx.x * blockDim.x + threadIdx.x;
  int e = t >> 6;
  int lane = t & 63;
  if (e >= E) return;
  int s = src[e];
  int d = dst[e];
  const float2 a = *(const float2*)(h + (size_t)s * D + 2 * lane);
  const float2 b = *(const float2*)(h + (size_t)d * D + 2 * lane);
  float part = a.x * b.x + a.y * b.y;
#pragma unroll
  for (int off = 32; off > 0; off >>= 1) part += __shfl_xor(part, off);
  float alpha = 1.0f / (1.0f + expf(-part));
  float* drow = aggr + (size_t)d * D + 2 * lane;
  atomicAdd(drow, alpha * a.x);
  atomicAdd(drow + 1, alpha * a.y);
}

extern "C" void kernel_launch(void* const* d_in, const int* in_sizes, int n_in,
                              void* d_out, int out_size, void* d_ws, size_t ws_size,
                              hipStream_t stream) {
  const float* x = (const float*)d_in[0];
  const int* ei = (const int*)d_in[1];
  int N = in_sizes[0] / D;   // 50000
  int E = in_sizes[1] / 2;   // 800000
  const int* src = ei;
  const int* dst = ei + E;
  float* out = (float*)d_out;
  size_t ND = (size_t)N * D;

  // noise_keys = jax.random.split(jax.random.key(1), 3)  [threefry_partitionable]
  uint32_t nk0[3], nk1[3];
  for (int k = 0; k < 3; ++k)
    threefry2x32(0u, 1u, 0u, (uint32_t)k, &nk0[k], &nk1[k]);

  int rowBlocks = (int)((ND / 2 + 255) / 256);          // one wave per row
  int edgeBlocks = (int)(((size_t)E * 64 + 255) / 256); // one wave per edge

  // out[0] = normalize(x)
  hipLaunchKernelGGL(norm_kernel, dim3(rowBlocks), dim3(256), 0, stream,
                     x, out, N, 0u, 0u, 0);
  // zero accumulators for hops 1..3 (d_out is poisoned 0xAA)
  hipMemsetAsync(out + ND, 0, 3 * ND * sizeof(float), stream);

  for (int k = 0; k < 3; ++k) {
    const float* hk = out + (size_t)k * ND;
    float* hk1 = out + (size_t)(k + 1) * ND;
    hipLaunchKernelGGL(edge_kernel, dim3(edgeBlocks), dim3(256), 0, stream,
                       hk, src, dst, hk1, E);
    hipLaunchKernelGGL(norm_kernel, dim3(rowBlocks), dim3(256), 0, stream,
                       hk1, hk1, N, nk0[k], nk1[k], 1);
  }
}

// Round 2
// 715.647 us; speedup vs baseline: 3.0614x; 3.0614x over previous
//
#include <hip/hip_runtime.h>
#include <cstdint>
#include <cstddef>

#define D 128

// ---------------- Threefry-2x32 (JAX/Random123), host+device ----------------
__host__ __device__ inline uint32_t rotl32(uint32_t v, int d) {
  return (v << d) | (v >> (32 - d));
}

__host__ __device__ inline void threefry2x32(uint32_t k0, uint32_t k1,
                                             uint32_t x0, uint32_t x1,
                                             uint32_t* o0, uint32_t* o1) {
  uint32_t k2 = k0 ^ k1 ^ 0x1BD11BDAu;
  x0 += k0; x1 += k1;
#define TF_RND(r) x0 += x1; x1 = rotl32(x1, (r)); x1 ^= x0;
  TF_RND(13) TF_RND(15) TF_RND(26) TF_RND(6)
  x0 += k1; x1 += k2 + 1u;
  TF_RND(17) TF_RND(29) TF_RND(16) TF_RND(24)
  x0 += k2; x1 += k0 + 2u;
  TF_RND(13) TF_RND(15) TF_RND(26) TF_RND(6)
  x0 += k0; x1 += k1 + 3u;
  TF_RND(17) TF_RND(29) TF_RND(16) TF_RND(24)
  x0 += k1; x1 += k2 + 4u;
  TF_RND(13) TF_RND(15) TF_RND(26) TF_RND(6)
  x0 += k2; x1 += k0 + 5u;
#undef TF_RND
  *o0 = x0; *o1 = x1;
}

// XLA ErfInv32 (Giles) — matches lax.erf_inv lowering for f32.
__device__ inline float erfinv_f32(float x) {
  float w = -log1pf(-x * x);
  float p;
  if (w < 5.0f) {
    w = w - 2.5f;
    p = 2.81022636e-08f;
    p = fmaf(p, w, 3.43273939e-07f);
    p = fmaf(p, w, -3.5233877e-06f);
    p = fmaf(p, w, -4.39150654e-06f);
    p = fmaf(p, w, 0.00021858087f);
    p = fmaf(p, w, -0.00125372503f);
    p = fmaf(p, w, -0.00417768164f);
    p = fmaf(p, w, 0.246640727f);
    p = fmaf(p, w, 1.50140941f);
  } else {
    w = sqrtf(w) - 3.0f;
    p = -0.000200214257f;
    p = fmaf(p, w, 0.000100950558f);
    p = fmaf(p, w, 0.00134934322f);
    p = fmaf(p, w, -0.00367342844f);
    p = fmaf(p, w, 0.00573950773f);
    p = fmaf(p, w, -0.0076224613f);
    p = fmaf(p, w, 0.00943887047f);
    p = fmaf(p, w, 1.00167406f);
    p = fmaf(p, w, 2.83297682f);
  }
  return p * x;
}

__device__ inline float jax_normal_elem(uint32_t k0, uint32_t k1, uint32_t idx) {
  uint32_t o0, o1;
  threefry2x32(k0, k1, 0u, idx, &o0, &o1);
  uint32_t bits = o0 ^ o1;
  float f = __uint_as_float((bits >> 9) | 0x3F800000u) - 1.0f;  // [0,1)
  float u = f * 2.0f + (-0.99999994f);
  u = fmaxf(-0.99999994f, u);
  return 1.41421356237309505f * erfinv_f32(u);
}

// ---------------- CSR build (per launch; edge_index fixed within launch) ----
__global__ __launch_bounds__(256) void hist_kernel(
    const int* __restrict__ dst, int* __restrict__ counts, int E) {
  int t = blockIdx.x * blockDim.x + threadIdx.x;
  if (t < E) atomicAdd(&counts[dst[t]], 1);
}

// Single-block in-place exclusive scan; also writes cursor copy and counts[N]=E.
__global__ __launch_bounds__(256) void scan_kernel(
    int* __restrict__ counts, int* __restrict__ cursor, int N, int E) {
  __shared__ int partial[256];
  int tid = threadIdx.x;
  int chunk = (N + 255) / 256;
  int lo = tid * chunk, hi = min(lo + chunk, N);
  int sum = 0;
  for (int i = lo; i < hi; ++i) sum += counts[i];
  partial[tid] = sum;
  __syncthreads();
  if (tid == 0) {
    int run = 0;
    for (int i = 0; i < 256; ++i) { int t = partial[i]; partial[i] = run; run += t; }
  }
  __syncthreads();
  int run = partial[tid];
  for (int i = lo; i < hi; ++i) {
    int c = counts[i];
    counts[i] = run;
    cursor[i] = run;
    run += c;
  }
  if (tid == 0) counts[N] = E;
}

__global__ __launch_bounds__(256) void scatter_kernel(
    const int* __restrict__ src, const int* __restrict__ dst,
    int* __restrict__ cursor, int* __restrict__ sorted_src, int E) {
  int t = blockIdx.x * blockDim.x + threadIdx.x;
  if (t < E) {
    int d = dst[t];
    int pos = atomicAdd(&cursor[d], 1);
    sorted_src[pos] = src[t];
  }
}

// ---------------- out[0] = normalize(x): one wave per row -------------------
__global__ __launch_bounds__(256) void norm_kernel(
    const float* __restrict__ in, float* __restrict__ out, int N) {
  int t = blockIdx.x * blockDim.x + threadIdx.x;
  int row = t >> 6;
  int lane = t & 63;
  if (row >= N) return;
  size_t base = (size_t)row * D + 2 * lane;
  float2 v = *(const float2*)(in + base);
  float ss = v.x * v.x + v.y * v.y;
#pragma unroll
  for (int off = 32; off > 0; off >>= 1) ss += __shfl_xor(ss, off);
  float denom = fmaxf(sqrtf(ss), 1e-12f);
  *(float2*)(out + base) = make_float2(v.x / denom, v.y / denom);
}

// ---------------- Fused hop: gather + gate + aggregate + noise + normalize --
// One wave per dst row. h[dst] and accumulator live in registers; each edge's
// h[src] row is loaded once and used for both the dot and the accumulation.
__global__ __launch_bounds__(256) void hop_kernel(
    const float* __restrict__ hprev, float* __restrict__ hout,
    const int* __restrict__ offsets, const int* __restrict__ sorted_src,
    int N, uint32_t k0, uint32_t k1) {
  int w = (blockIdx.x * blockDim.x + threadIdx.x) >> 6;
  int lane = threadIdx.x & 63;
  if (w >= N) return;
  size_t base = (size_t)w * D + 2 * lane;
  const float2 b = *(const float2*)(hprev + base);
  float accx = 0.f, accy = 0.f;
  int j = offsets[w], jhi = offsets[w + 1];

  // software-pipelined gather loop
  float2 a;
  if (j < jhi) {
    int s = sorted_src[j];
    a = *(const float2*)(hprev + (size_t)s * D + 2 * lane);
  }
  while (j < jhi) {
    int jn = j + 1;
    float2 an;
    if (jn < jhi) {
      int sn = sorted_src[jn];
      an = *(const float2*)(hprev + (size_t)sn * D + 2 * lane);
    }
    float part = a.x * b.x + a.y * b.y;
#pragma unroll
    for (int off = 32; off > 0; off >>= 1) part += __shfl_xor(part, off);
    float alpha = 1.0f / (1.0f + expf(-part));
    accx = fmaf(alpha, a.x, accx);
    accy = fmaf(alpha, a.y, accy);
    a = an;
    j = jn;
  }

  // noise (bit-exact jax.random.normal) + L2 normalize epilogue
  uint32_t idx = (uint32_t)base;
  accx += 0.1f * jax_normal_elem(k0, k1, idx);
  accy += 0.1f * jax_normal_elem(k0, k1, idx + 1u);
  float ss = accx * accx + accy * accy;
#pragma unroll
  for (int off = 32; off > 0; off >>= 1) ss += __shfl_xor(ss, off);
  float denom = fmaxf(sqrtf(ss), 1e-12f);
  *(float2*)(hout + base) = make_float2(accx / denom, accy / denom);
}

extern "C" void kernel_launch(void* const* d_in, const int* in_sizes, int n_in,
                              void* d_out, int out_size, void* d_ws, size_t ws_size,
                              hipStream_t stream) {
  const float* x = (const float*)d_in[0];
  const int* ei = (const int*)d_in[1];
  int N = in_sizes[0] / D;   // 50000
  int E = in_sizes[1] / 2;   // 800000
  const int* src = ei;
  const int* dst = ei + E;
  float* out = (float*)d_out;
  size_t ND = (size_t)N * D;

  // ws layout: offsets[N+1] | cursor[N] | sorted_src[E]  (~3.6 MB)
  int* offsets = (int*)d_ws;
  int* cursor = offsets + (N + 1);
  int* sorted_src = cursor + N;

  // noise_keys = jax.random.split(jax.random.key(1), 3)  [threefry_partitionable]
  uint32_t nk0[3], nk1[3];
  for (int k = 0; k < 3; ++k)
    threefry2x32(0u, 1u, 0u, (uint32_t)k, &nk0[k], &nk1[k]);

  int eBlocks = (E + 255) / 256;
  int waveBlocks = (int)(((size_t)N * 64 + 255) / 256);  // one wave per row

  // CSR build (reused by all 3 hops)
  hipMemsetAsync(offsets, 0, (size_t)(N + 1) * sizeof(int), stream);
  hipLaunchKernelGGL(hist_kernel, dim3(eBlocks), dim3(256), 0, stream, dst, offsets, E);
  hipLaunchKernelGGL(scan_kernel, dim3(1), dim3(256), 0, stream, offsets, cursor, N, E);
  hipLaunchKernelGGL(scatter_kernel, dim3(eBlocks), dim3(256), 0, stream,
                     src, dst, cursor, sorted_src, E);

  // out[0] = normalize(x)
  hipLaunchKernelGGL(norm_kernel, dim3(waveBlocks), dim3(256), 0, stream, x, out, N);

  for (int k = 0; k < 3; ++k) {
    const float* hk = out + (size_t)k * ND;
    float* hk1 = out + (size_t)(k + 1) * ND;
    hipLaunchKernelGGL(hop_kernel, dim3(waveBlocks), dim3(256), 0, stream,
                       hk, hk1, offsets, sorted_src, N, nk0[k], nk1[k]);
  }
}